// Round 8
// baseline (1090.404 us; speedup 1.0000x reference)
//
#include <hip/hip_runtime.h>
#include <stdint.h>

typedef unsigned long long ull;

#define TT 2048

// ---------------- compile-time threefry2x32 (JAX semantics) ----------------
struct TF2 { uint32_t x, y; };

constexpr TF2 tf2x32(uint32_t k0, uint32_t k1, uint32_t x0, uint32_t x1) {
  uint32_t ks2 = k0 ^ k1 ^ 0x1BD11BDAu;
  x0 += k0; x1 += k1;
#define TFR_(r) x0 += x1; x1 = __builtin_rotateleft32(x1, r); x1 ^= x0;
  TFR_(13) TFR_(15) TFR_(26) TFR_(6)
  x0 += k1;  x1 += ks2 + 1u;
  TFR_(17) TFR_(29) TFR_(16) TFR_(24)
  x0 += ks2; x1 += k0 + 2u;
  TFR_(13) TFR_(15) TFR_(26) TFR_(6)
  x0 += k0;  x1 += k1 + 3u;
  TFR_(17) TFR_(29) TFR_(16) TFR_(24)
  x0 += k1;  x1 += ks2 + 4u;
  TFR_(13) TFR_(15) TFR_(26) TFR_(6)
  x0 += ks2; x1 += k0 + 5u;
#undef TFR_
  return {x0, x1};
}

struct Half_ { uint32_t a[1024]; uint32_t b[1024]; uint32_t k0, k1; };

constexpr Half_ make_half(uint32_t k0, uint32_t k1) {
  Half_ h{};
  for (int t = 0; t < 1024; ++t) {
    TF2 nk = tf2x32(k0, k1, 0u, 0u);
    TF2 sb = tf2x32(k0, k1, 0u, 1u);
    h.a[t] = sb.x; h.b[t] = sb.y;
    k0 = nk.x; k1 = nk.y;
  }
  h.k0 = k0; h.k1 = k1;
  return h;
}

namespace ckeys {
constexpr Half_ H0 = make_half(0u, 42u);
constexpr Half_ H1 = make_half(H0.k0, H0.k1);
}
__constant__ Half_ dH0 = ckeys::H0;
__constant__ Half_ dH1 = ckeys::H1;

// ---------------- XLA fast-tanh replica ----------------
__device__ __forceinline__ float tanh_xla(float x) {
#pragma clang fp contract(off)
  float ax = fabsf(x);
  float xc = fminf(fmaxf(x, -7.90531110763549805f), 7.90531110763549805f);
  float x2 = xc * xc;
  float p = fmaf(x2, -2.76076847742355e-16f, 2.00018790482477e-13f);
  p = fmaf(x2, p, -8.60467152213735e-11f);
  p = fmaf(x2, p, 5.12229709037114e-08f);
  p = fmaf(x2, p, 1.48572235717979e-05f);
  p = fmaf(x2, p, 6.37261928875436e-04f);
  p = fmaf(x2, p, 4.89352455891786e-03f);
  p = xc * p;
  float q = fmaf(x2, 1.19825839466702e-06f, 1.18534705686654e-04f);
  q = fmaf(x2, q, 2.26843463243900e-03f);
  q = fmaf(x2, q, 4.89352518554385e-03f);
  return (ax < 0.0004f) ? x : (p / q);
}

__device__ __forceinline__ float sig_ref(float z) {
#pragma clang fp contract(off)
  float e = (float)exp(-(double)z);
  return 1.0f / (1.0f + e);
}

__device__ __forceinline__ uint32_t ford(float f) {
  uint32_t x = __float_as_uint(f);
  return (x & 0x80000000u) ? ~x : (x | 0x80000000u);
}
__device__ __forceinline__ float fdec(uint32_t k) {
  uint32_t b = (k & 0x80000000u) ? (k & 0x7fffffffu) : ~k;
  return __uint_as_float(b);
}

// tau = max f32 z with sig_ref(z) <= u  (spike <=> z > tau)
__device__ float find_tau(float u) {
  if (!(u > 0.0f)) return -1.0e30f;
  double zg = log((double)u / (1.0 - (double)u));
  float zgf = (float)zg;
  zgf = fminf(fmaxf(zgf, -90.0f), 90.0f);
  uint32_t kc = ford(zgf);
  uint32_t klo = kc - 96u, khi = kc + 96u;
  if (!(sig_ref(fdec(klo)) <= u)) klo = ford(-95.0f);
  if (!(sig_ref(fdec(khi)) > u))  khi = ford(95.0f);
  while (khi - klo > 1u) {
    uint32_t km = klo + ((khi - klo) >> 1);
    if (sig_ref(fdec(km)) <= u) klo = km; else khi = km;
  }
  return fdec(klo);
}

// ---------------- pre kernel ----------------
__global__ void ap_pre_kernel(const float* __restrict__ V, const float* __restrict__ D,
                              const float* __restrict__ w1, const float* __restrict__ b1,
                              const float* __restrict__ w2, const float* __restrict__ b2,
                              const float* __restrict__ Wr,
                              float* __restrict__ zb, float* __restrict__ tauA,
                              float* __restrict__ rk, uint32_t* flags) {
#pragma clang fp contract(off)
  int tid = threadIdx.x;
  int blk = blockIdx.x;
  if (blk < 512) {
    int idx = blk * 256 + tid;          // idx = b*2048 + t
    int b = idx >> 11, t = idx & 2047;
    float v = V[idx], dd = D[idx];
    float acc = 0.f;
#pragma unroll
    for (int h = 0; h < 5; ++h) {
      float m = fmaf(w1[2 * h + 1], dd, w1[2 * h] * v) + b1[h];
      float th = tanh_xla(m);
      acc = (h == 0) ? (w2[0] * th) : fmaf(w2[h], th, acc);
    }
    float z0 = acc + b2[0];
    uint32_t ka = (t < 1024) ? dH0.a[t] : dH1.a[t - 1024];
    uint32_t kb = (t < 1024) ? dH0.b[t] : dH1.b[t - 1024];
    TF2 o = tf2x32(ka, kb, 0u, (uint32_t)b);
    uint32_t bits = o.x ^ o.y;
    float u = __uint_as_float((bits >> 9) | 0x3f800000u) - 1.0f;
    zb[t * 64 + b] = z0;
    tauA[t * 64 + b] = find_tau(u);
  } else if (blk < 514) {
    int d = (blk - 512) * 256 + tid;    // rk[d] for lag d (1..501), else 0
    float val = 0.f;
    if (d >= 1 && d <= 501) {
      double raw = 7.5 * log((double)(d - 1) + 1.0 + 1e-7);
      float a = 0.f;
      for (int i = 0; i < 30; ++i) {
        double phi = (0.5 * 3.141592653589793) * (double)i;
        float bf;
        if (raw < phi - 3.141592653589793 || raw > phi + 3.141592653589793) bf = 0.f;
        else bf = (float)(0.5 * cos(raw - phi) + 0.5);
        a = fmaf(Wr[i], bf, a);
      }
      val = a;
    }
    rk[d] = val;
  } else {
    // flags[0]=stager progress (windows done); flags[1+c]=conv done count (==4 ready), c=0..63
    if (tid < 80) flags[tid] = 0u;
    if (tid >= 1 && tid <= 5) flags[tid] = 4u;   // chunks 0..4 have no far-conv taps
  }
}

// ---------------- main kernel ----------------
// 32-slot windows (64 total). block 0 (one CU, LDS handshakes):
//   wave0   = decision: lags 1..66 (8 byte-LUTs, 64-bit history) + {combo,P89,tau} f4 ring
//   waves1-4= helpers (slot-striped, 8 slots each): lags 67..162 -> f4={zb+acc, e8+e9, tau, 0}
//   wave5   = stager: 32 ballots/window -> sw + flags[0]
// blocks 1..236: far conv (lags 163..501), chunks 5..63, 4 blocks/chunk (chunk c = slots 32c..32c+31)
__global__ void __launch_bounds__(512, 1)
ap_main_kernel(float* zb, const float* __restrict__ tauA,
               const float* __restrict__ rk, float* __restrict__ zarr,
               ull* __restrict__ sw, uint32_t* flags) {
  // block0 LDS
  __shared__ float lutS[8 * 256];     // decision o=0..7: bit i -> rk[3+8o+i] (R4 tables)
  __shared__ float lutM[12 * 256];    // helper o=8..19: bit i -> rk[10+8o-i] (R7-verified)
  __shared__ float4 comboQ[64 * 64];  // ring (slot&63, lane): {combo, P89, tau, 0}
  __shared__ uint32_t snapR[16 * 64]; // window w&15: bit j = spike_{32w+31-j}
  __shared__ int winDoneH[4][8];      // gen-tagged per helper: == v+1 when its slice of window v done
  __shared__ int progLds;             // 32w+32 after decision window w
  // conv LDS
  __shared__ ull swL[384];
  __shared__ uint32_t colb[64 * 13];
  __shared__ float rkL[512];

  int tid = threadIdx.x;
  int lane = tid & 63;

  if (blockIdx.x == 0) {
    // ---- prologue: build LUTs (all 512 threads) ----
    for (int e = tid; e < 8 * 256; e += 512) {
      int o = e >> 8, vb = e & 255;
      float s = 0.f;
      for (int i = 0; i < 8; ++i)
        if (vb & (1 << i)) s += rk[3 + 8 * o + i];
      lutS[e] = s;
    }
    for (int e = tid; e < 12 * 256; e += 512) {
      int o = 8 + (e >> 8), vb = e & 255;
      float s = 0.f;
      for (int i = 0; i < 8; ++i)
        if ((vb >> i) & 1) s += rk[10 + 8 * o - i];
      lutM[e] = s;
    }
    if (tid < 32) winDoneH[tid >> 3][tid & 7] = 0;
    if (tid == 0) progLds = 0;
    __syncthreads();

    int wv = tid >> 6;

    if (wv == 0) {
      // ================= DECISION WAVE =================
      float rk1 = rk[1], rk2 = rk[2];
      auto pollWin = [&](int vv) {
        int slot = vv & 7, gen = vv + 1;
        for (;;) {
          int ok = 1;
#pragma unroll
          for (int h = 0; h < 4; ++h)
            ok &= (__hip_atomic_load(&winDoneH[h][slot], __ATOMIC_ACQUIRE,
                                     __HIP_MEMORY_SCOPE_WORKGROUP) == gen);
          if (ok) break;
          __builtin_amdgcn_s_sleep(1);
        }
      };
      pollWin(0);
      float4 cp4[2];
      cp4[0] = comboQ[0 * 64 + lane];
      cp4[1] = comboQ[1 * 64 + lane];
      float l[2][8];
#pragma unroll
      for (int k = 0; k < 8; ++k) { l[0][k] = 0.f; l[1][k] = 0.f; }
      uint32_t m0 = 0, m1 = 0;
      float s1f = 0.f, s2f = 0.f;

      for (int w = 0; w < 64; ++w) {
        float* zarrW = zarr + w * 2048 + lane;
#pragma unroll
        for (int q = 0; q < 32; ++q) {
          if (q == 30 && w + 1 < 64) pollWin(w + 1);   // helpers(w+1) gated on end of w-1: no cycle
          int p = q & 1;
          float4 f4 = cp4[p];          // {combo=zb+acc(83..162), P89(67..82), tau, 0} slot t=32w+q
          // R4-exact tree
          float a1 = l[p][0] + l[p][1];
          float a2 = l[p][2] + l[p][3];
          float A  = a1 + a2;
          float b1_ = l[p][4] + l[p][5];
          float B  = b1_ + (l[p][6] + l[p][7]);
          float g  = (A + B) + f4.y;
          float z  = f4.x + g;
          z = fmaf(rk2, s2f, z);
          z = fmaf(rk1, s1f, z);
          bool sp = z > f4.z;
          zarrW[q * 64] = z;           // fire-and-forget
          // prefetch f4 for slot t+2
          cp4[p] = comboQ[(((32 * w + q + 2) & 63) << 6) + lane];
          // LUT reads for slot t+2 from PRE-shift 64-bit history (bit j = spike_{t-1-j})
          l[p][0] = lutS[         (m0        & 255u)];
          l[p][1] = lutS[ 256 + ((m0 >> 8 ) & 255u)];
          l[p][2] = lutS[ 512 + ((m0 >> 16) & 255u)];
          l[p][3] = lutS[ 768 + ( m0 >> 24         )];
          l[p][4] = lutS[1024 + ( m1        & 255u)];
          l[p][5] = lutS[1280 + ((m1 >> 8 ) & 255u)];
          l[p][6] = lutS[1536 + ((m1 >> 16) & 255u)];
          l[p][7] = lutS[1792 + ( m1 >> 24         )];
          // shift 64-bit history, insert this spike
          m1 = __builtin_amdgcn_alignbit(m1, m0, 31);
          m0 = (m0 << 1) | (sp ? 1u : 0u);
          s2f = s1f;
          s1f = sp ? 1.0f : 0.0f;
        }
        snapR[(w & 15) * 64 + lane] = m0;   // bit j = spike_{32w+31-j}
        if (lane == 0)
          __hip_atomic_store(&progLds, 32 * w + 32, __ATOMIC_RELEASE,
                             __HIP_MEMORY_SCOPE_WORKGROUP);
      }
      return;
    } else if (wv >= 1 && wv <= 4) {
      // ================= HELPERS: lags 67..162, slots 8h..8h+7 of every window =================
      int h = wv - 1;
      int q0 = 8 * h;
      for (int v = 0; v < 64; ++v) {
        if (v >= 2) {
          int tgt = 32 * (v - 1);      // end of window v-2
          while (__hip_atomic_load(&progLds, __ATOMIC_ACQUIRE,
                                   __HIP_MEMORY_SCOPE_WORKGROUP) < tgt)
            __builtin_amdgcn_s_sleep(1);
        }
        if (v >= 5) {
          while (__hip_atomic_load(&flags[1 + v], __ATOMIC_ACQUIRE,
                                   __HIP_MEMORY_SCOPE_AGENT) < 4u)
            __builtin_amdgcn_s_sleep(2);
        }
        // ascending spike words, windows v-6..v-2  (r[k] bit i = spike_{32(v-6)+32k+i})
        uint32_t r[5];
#pragma unroll
        for (int j = 0; j < 5; ++j) {
          int g = v - 6 + j;
          r[j] = (g >= 0) ? __builtin_bitreverse32(snapR[(g & 15) * 64 + lane]) : 0u;
        }
        const float* zvp = zb   + (32 * v + q0) * 64 + lane;
        const float* tvp = tauA + (32 * v + q0) * 64 + lane;
        float zv[8], tv[8];
#pragma unroll
        for (int qq = 0; qq < 8; ++qq) { zv[qq] = zvp[qq * 64]; tv[qq] = tvp[qq * 64]; }
#pragma unroll
        for (int qq = 0; qq < 8; ++qq) {
          int q = q0 + qq;
          float e8 = 0.f, e9 = 0.f, acc = 0.f;
#pragma unroll
          for (int o = 8; o < 20; ++o) {
            int pos = q + 182 - 8 * o;   // byte bit i = spike_{s-10-8o+i}, base 32(v-6)
            int k = pos >> 5, sh = pos & 31;
            uint32_t byt;
            if (sh <= 24) byt = (r[k] >> sh) & 255u;
            else          byt = __builtin_amdgcn_alignbit(r[k + 1], r[k], (uint32_t)sh) & 255u;
            float ent = lutM[(o - 8) * 256 + byt];
            if (o == 8) e8 = ent;
            else if (o == 9) e9 = ent;
            else acc += ent;             // o=10..19 ascending, R4 order
          }
          float4 f4;
          f4.x = zv[qq] + acc;           // R4's (zbR + cpipe)
          f4.y = e8 + e9;                // R4's (l8 + l9)
          f4.z = tv[qq];
          f4.w = 0.f;
          comboQ[(((32 * v + q) & 63) << 6) + lane] = f4;
        }
        __hip_atomic_store(&winDoneH[h][v & 7], v + 1, __ATOMIC_RELEASE,
                           __HIP_MEMORY_SCOPE_WORKGROUP);
      }
      return;
    } else if (wv == 5) {
      // ================= STAGER: snapR -> ballots -> sw + flags[0] =================
      for (int u = 0; u < 64; ++u) {
        while (__hip_atomic_load(&progLds, __ATOMIC_ACQUIRE,
                                 __HIP_MEMORY_SCOPE_WORKGROUP) < 32 * u + 32)
          __builtin_amdgcn_s_sleep(2);
        uint32_t sn = snapR[(u & 15) * 64 + lane];
#pragma unroll
        for (int i = 0; i < 32; ++i) {
          uint32_t bit = (sn >> (31 - i)) & 1u;
          ull bal = __ballot(bit != 0u);
          if (lane == 0) sw[32 * u + i] = bal;
        }
        if (lane == 0)
          __hip_atomic_store(&flags[0], (uint32_t)(u + 1), __ATOMIC_RELEASE,
                             __HIP_MEMORY_SCOPE_AGENT);
      }
      return;
    }
    return;  // waves 6,7 idle
  }

  // ================= CONV BLOCKS: far lags 163..501 =================
  int c = 5 + ((int)blockIdx.x - 1) / 4;
  int qq = ((int)blockIdx.x - 1) & 3;
  int T0 = 32 * c + 8 * qq;
  int s0 = T0 - 501;
  if (tid == 0) {
    while ((int)__hip_atomic_load(&flags[0], __ATOMIC_ACQUIRE,
                                  __HIP_MEMORY_SCOPE_AGENT) < c - 4)
      __builtin_amdgcn_s_sleep(8);
  }
  __syncthreads();
  for (int i = tid; i < 384; i += 512) {
    int s = s0 + i;
    swL[i] = (s >= 0 && i < 346) ? sw[s] : 0ull;
  }
  rkL[tid] = rk[tid];
  __syncthreads();
  {
    int w8 = tid >> 6;
#pragma unroll
    for (int rep = 0; rep < 2; ++rep) {
      int W = w8 + 8 * rep;
      if (W < 12) {
        uint32_t word = 0;
        for (int i2 = 0; i2 < 32; ++i2) {
          ull v = swL[32 * W + i2];
          uint32_t bit = (uint32_t)((v >> lane) & 1ull);
          word |= bit << i2;
        }
        colb[lane * 13 + W] = word;
      }
    }
  }
  __syncthreads();
  {
    int tl = tid >> 6;           // 0..7
    int b = tid & 63;
    uint32_t cw[12];
#pragma unroll
    for (int W = 0; W < 12; ++W) cw[W] = colb[b * 13 + W];
    uint32_t A[11];
#pragma unroll
    for (int W = 0; W < 11; ++W)
      A[W] = __builtin_amdgcn_alignbit(cw[W + 1], cw[W], (uint32_t)tl);
    float acc = 0.f;
#pragma unroll 4
    for (int k = 0; k < 339; ++k) {   // lag = 501-k (501..163)
      float bv = (float)((A[k >> 5] >> (k & 31)) & 1u);
      acc = fmaf(bv, rkL[501 - k], acc);
    }
    int t = T0 + tl;
    zb[t * 64 + b] += acc;
  }
  __syncthreads();
  if (tid == 0)
    __hip_atomic_fetch_add(&flags[1 + c], 1u, __ATOMIC_RELEASE,
                           __HIP_MEMORY_SCOPE_AGENT);
}

// ---------------- post kernel ----------------
__global__ void ap_post_kernel(const float* __restrict__ zarr, const float* __restrict__ tauA,
                               float* __restrict__ out) {
#pragma clang fp contract(off)
  int idx = blockIdx.x * 256 + threadIdx.x;   // b*2048 + t
  int b = idx >> 11, t = idx & 2047;
  float z = zarr[t * 64 + b];
  float tau = tauA[t * 64 + b];
  out[idx] = (z > tau) ? 1.0f : 0.0f;
  out[131072 + idx] = 1.0f / (1.0f + __expf(-z));
}

extern "C" void kernel_launch(void* const* d_in, const int* in_sizes, int n_in,
                              void* d_out, int out_size, void* d_ws, size_t ws_size,
                              hipStream_t stream) {
  (void)in_sizes; (void)n_in; (void)out_size; (void)ws_size;
  const float* V  = (const float*)d_in[0];
  const float* D  = (const float*)d_in[1];
  const float* w1 = (const float*)d_in[2];
  const float* b1 = (const float*)d_in[3];
  const float* w2 = (const float*)d_in[4];
  const float* b2 = (const float*)d_in[5];
  const float* Wr = (const float*)d_in[6];

  char* w = (char*)d_ws;
  float*    zb    = (float*)w;                 // [2048*64]  nn + far-conv (lags>=163)
  float*    tauA  = (float*)(w + 0x080000);    // [2048*64]
  float*    zarr  = (float*)(w + 0x100000);    // [2048*64]
  ull*      swp   = (ull*)(w + 0x180000);      // [2048]
  float*    rk    = (float*)(w + 0x184000);    // [512]
  uint32_t* flags = (uint32_t*)(w + 0x184800); // [80]

  ap_pre_kernel<<<515, 256, 0, stream>>>(V, D, w1, b1, w2, b2, Wr, zb, tauA, rk, flags);
  ap_main_kernel<<<237, 512, 0, stream>>>(zb, tauA, rk, zarr, swp, flags);
  ap_post_kernel<<<512, 256, 0, stream>>>(zarr, tauA, (float*)d_out);
}

// Round 9
// 458.286 us; speedup vs baseline: 2.3793x; 2.3793x over previous
//
#include <hip/hip_runtime.h>
#include <stdint.h>

typedef unsigned long long ull;

#define TT 2048

// ---------------- compile-time threefry2x32 (JAX semantics) ----------------
struct TF2 { uint32_t x, y; };

constexpr TF2 tf2x32(uint32_t k0, uint32_t k1, uint32_t x0, uint32_t x1) {
  uint32_t ks2 = k0 ^ k1 ^ 0x1BD11BDAu;
  x0 += k0; x1 += k1;
#define TFR_(r) x0 += x1; x1 = __builtin_rotateleft32(x1, r); x1 ^= x0;
  TFR_(13) TFR_(15) TFR_(26) TFR_(6)
  x0 += k1;  x1 += ks2 + 1u;
  TFR_(17) TFR_(29) TFR_(16) TFR_(24)
  x0 += ks2; x1 += k0 + 2u;
  TFR_(13) TFR_(15) TFR_(26) TFR_(6)
  x0 += k0;  x1 += k1 + 3u;
  TFR_(17) TFR_(29) TFR_(16) TFR_(24)
  x0 += k1;  x1 += ks2 + 4u;
  TFR_(13) TFR_(15) TFR_(26) TFR_(6)
  x0 += ks2; x1 += k0 + 5u;
#undef TFR_
  return {x0, x1};
}

struct Half_ { uint32_t a[1024]; uint32_t b[1024]; uint32_t k0, k1; };

constexpr Half_ make_half(uint32_t k0, uint32_t k1) {
  Half_ h{};
  for (int t = 0; t < 1024; ++t) {
    TF2 nk = tf2x32(k0, k1, 0u, 0u);
    TF2 sb = tf2x32(k0, k1, 0u, 1u);
    h.a[t] = sb.x; h.b[t] = sb.y;
    k0 = nk.x; k1 = nk.y;
  }
  h.k0 = k0; h.k1 = k1;
  return h;
}

namespace ckeys {
constexpr Half_ H0 = make_half(0u, 42u);
constexpr Half_ H1 = make_half(H0.k0, H0.k1);
}
__constant__ Half_ dH0 = ckeys::H0;
__constant__ Half_ dH1 = ckeys::H1;

// ---------------- XLA fast-tanh replica ----------------
__device__ __forceinline__ float tanh_xla(float x) {
#pragma clang fp contract(off)
  float ax = fabsf(x);
  float xc = fminf(fmaxf(x, -7.90531110763549805f), 7.90531110763549805f);
  float x2 = xc * xc;
  float p = fmaf(x2, -2.76076847742355e-16f, 2.00018790482477e-13f);
  p = fmaf(x2, p, -8.60467152213735e-11f);
  p = fmaf(x2, p, 5.12229709037114e-08f);
  p = fmaf(x2, p, 1.48572235717979e-05f);
  p = fmaf(x2, p, 6.37261928875436e-04f);
  p = fmaf(x2, p, 4.89352455891786e-03f);
  p = xc * p;
  float q = fmaf(x2, 1.19825839466702e-06f, 1.18534705686654e-04f);
  q = fmaf(x2, q, 2.26843463243900e-03f);
  q = fmaf(x2, q, 4.89352518554385e-03f);
  return (ax < 0.0004f) ? x : (p / q);
}

__device__ __forceinline__ float sig_ref(float z) {
#pragma clang fp contract(off)
  float e = (float)exp(-(double)z);
  return 1.0f / (1.0f + e);
}

__device__ __forceinline__ uint32_t ford(float f) {
  uint32_t x = __float_as_uint(f);
  return (x & 0x80000000u) ? ~x : (x | 0x80000000u);
}
__device__ __forceinline__ float fdec(uint32_t k) {
  uint32_t b = (k & 0x80000000u) ? (k & 0x7fffffffu) : ~k;
  return __uint_as_float(b);
}

// tau = max f32 z with sig_ref(z) <= u  (spike <=> z > tau)
__device__ float find_tau(float u) {
  if (!(u > 0.0f)) return -1.0e30f;
  double zg = log((double)u / (1.0 - (double)u));
  float zgf = (float)zg;
  zgf = fminf(fmaxf(zgf, -90.0f), 90.0f);
  uint32_t kc = ford(zgf);
  uint32_t klo = kc - 96u, khi = kc + 96u;
  if (!(sig_ref(fdec(klo)) <= u)) klo = ford(-95.0f);
  if (!(sig_ref(fdec(khi)) > u))  khi = ford(95.0f);
  while (khi - klo > 1u) {
    uint32_t km = klo + ((khi - klo) >> 1);
    if (sig_ref(fdec(km)) <= u) klo = km; else khi = km;
  }
  return fdec(klo);
}

// ---------------- pre kernel ----------------
__global__ void ap_pre_kernel(const float* __restrict__ V, const float* __restrict__ D,
                              const float* __restrict__ w1, const float* __restrict__ b1,
                              const float* __restrict__ w2, const float* __restrict__ b2,
                              const float* __restrict__ Wr,
                              float* __restrict__ zb, float* __restrict__ tauA,
                              float* __restrict__ rk, uint32_t* flags) {
#pragma clang fp contract(off)
  int tid = threadIdx.x;
  int blk = blockIdx.x;
  if (blk < 512) {
    int idx = blk * 256 + tid;          // idx = b*2048 + t
    int b = idx >> 11, t = idx & 2047;
    float v = V[idx], dd = D[idx];
    float acc = 0.f;
#pragma unroll
    for (int h = 0; h < 5; ++h) {
      float m = fmaf(w1[2 * h + 1], dd, w1[2 * h] * v) + b1[h];
      float th = tanh_xla(m);
      acc = (h == 0) ? (w2[0] * th) : fmaf(w2[h], th, acc);
    }
    float z0 = acc + b2[0];
    uint32_t ka = (t < 1024) ? dH0.a[t] : dH1.a[t - 1024];
    uint32_t kb = (t < 1024) ? dH0.b[t] : dH1.b[t - 1024];
    TF2 o = tf2x32(ka, kb, 0u, (uint32_t)b);
    uint32_t bits = o.x ^ o.y;
    float u = __uint_as_float((bits >> 9) | 0x3f800000u) - 1.0f;
    zb[t * 64 + b] = z0;
    tauA[t * 64 + b] = find_tau(u);
  } else if (blk < 514) {
    int d = (blk - 512) * 256 + tid;    // rk[d] for lag d (1..501), else 0
    float val = 0.f;
    if (d >= 1 && d <= 501) {
      double raw = 7.5 * log((double)(d - 1) + 1.0 + 1e-7);
      float a = 0.f;
      for (int i = 0; i < 30; ++i) {
        double phi = (0.5 * 3.141592653589793) * (double)i;
        float bf;
        if (raw < phi - 3.141592653589793 || raw > phi + 3.141592653589793) bf = 0.f;
        else bf = (float)(0.5 * cos(raw - phi) + 0.5);
        a = fmaf(Wr[i], bf, a);
      }
      val = a;
    }
    rk[d] = val;
  } else {
    // flags[0] = stager progress; flags[1+c] = conv-done count for chunk c (==4 ready)
    if (tid == 0) flags[0] = 0u;
    if (tid >= 1 && tid <= 64) {
      int c = tid - 1;
      flags[tid] = (c <= 4) ? 4u : 0u;   // chunks 0..4 have no far-conv taps
    }
  }
}

// ---------------- main kernel ----------------
// block 0: wave0 = decision (lags 1..82; lags 3..10 via fma queue, tables o=1..9 at dist 4),
//          wave1/wave2 = twins (lags 83..162, window parity), wave3 = stager, waves 4..7 idle.
// blocks 1..236: far conv (lags 163..501), chunks 5..63, 4 blocks/chunk.
__global__ void __launch_bounds__(512, 1)
ap_main_kernel(float* __restrict__ zb, const float* __restrict__ tauA,
               const float* __restrict__ rk, float* __restrict__ zarr,
               ull* __restrict__ sw, uint32_t* flags) {
  // block0 LDS
  __shared__ float lutS[20 * 256];     // o=0..9: bit i -> rk[3+8o+i]; o=10..19: bit i -> rk[3+8o+7-i]
  __shared__ uint32_t snapL[16 * 64];  // group g&15: bit j = spike_{16g+15-j}  (stager)
  __shared__ uint32_t snapA[16 * 64];  // bitreversed (twins)
  __shared__ float comboL[64 * 64];    // combo ring (s&63, lane): twin sum lags 83..162
  __shared__ int winDone[8];           // gen-tagged: winDone[w&7] == w+1 when window w done
  __shared__ int progLds;              // decision progress (t+1 after window end)
  // conv LDS
  __shared__ ull swL[384];
  __shared__ uint32_t colb[64 * 13];
  __shared__ float rkL[512];

  int tid = threadIdx.x;
  int lane = tid & 63;

  if (blockIdx.x == 0) {
    // ---- prologue: build LUTs (all 512 threads) ----
    for (int e = tid; e < 20 * 256; e += 512) {
      int o = e >> 8, vb = e & 255;
      float s = 0.f;
      if (o < 10) {
        for (int i = 0; i < 8; ++i)
          if (vb & (1 << i)) s += rk[3 + 8 * o + i];
      } else {
        for (int i = 0; i < 8; ++i)
          if (vb & (1 << i)) s += rk[3 + 8 * o + 7 - i];
      }
      lutS[e] = s;
    }
    if (tid < 8) winDone[tid] = 0;
    if (tid == 0) progLds = 0;
    __syncthreads();

    int wv = tid >> 6;

    if (wv == 0) {
      // ================= DECISION WAVE: lags 1..82 =================
      float rk1 = rk[1], rk2 = rk[2];
      float rkd[8];
#pragma unroll
      for (int i = 0; i < 8; ++i) rkd[i] = rk[3 + i];   // lags 3..10
      float zbR[2][16], tauR[2][16];
#pragma unroll
      for (int q = 0; q < 16; ++q) {
        zbR[0][q]  = zb[q * 64 + lane];
        tauR[0][q] = tauA[q * 64 + lane];
        zbR[1][q]  = zb[1024 + q * 64 + lane];
        tauR[1][q] = tauA[1024 + q * 64 + lane];
      }
      while (__hip_atomic_load(&winDone[0], __ATOMIC_ACQUIRE, __HIP_MEMORY_SCOPE_WORKGROUP) != 1)
        __builtin_amdgcn_s_sleep(1);
      float cpipe[4];
#pragma unroll
      for (int c = 0; c < 4; ++c) cpipe[c] = comboL[c * 64 + lane];
      float lB[4][9];
#pragma unroll
      for (int a = 0; a < 4; ++a)
#pragma unroll
        for (int k = 0; k < 9; ++k) lB[a][k] = 0.f;
      uint32_t m0 = 0, m1 = 0, m2 = 0;
      float s1f = 0.f, s2f = 0.f, s3f = 0.f, s4f = 0.f, s5f = 0.f,
            s6f = 0.f, s7f = 0.f, s8f = 0.f, s9f = 0.f, s10f = 0.f;

      for (int wp = 0; wp < 64; ++wp) {
#pragma unroll
        for (int half = 0; half < 2; ++half) {
          int w = 2 * wp + half;
          // poll twin for window w+1 (generation-tagged)
          if (w < 127) {
            int slot = (w + 1) & 7, gen = w + 2;
            while (__hip_atomic_load(&winDone[slot], __ATOMIC_ACQUIRE,
                                     __HIP_MEMORY_SCOPE_WORKGROUP) != gen)
              __builtin_amdgcn_s_sleep(1);
          }
          // far-conv readiness for the chunk we're about to prefetch (2 windows ahead)
          if (half == 0) {
            int c2 = (w + 2) >> 1;
            if (c2 >= 5 && c2 <= 63) {
              while ((int)__hip_atomic_load(&flags[1 + c2], __ATOMIC_ACQUIRE,
                                            __HIP_MEMORY_SCOPE_AGENT) < 4)
                __builtin_amdgcn_s_sleep(2);
            }
          }
          int wl = (w + 2 <= 127) ? (w + 2) : 127;
          const float* zbL  = zb + wl * 1024 + lane;
          const float* tauL = tauA + wl * 1024 + lane;
          float* zarrW = zarr + w * 1024 + lane;
          int wbase = (16 * w) & 63;
#pragma unroll
          for (int q = 0; q < 16; ++q) {
            int pq = q & 3;
            // e0 = lags 3..10 via fma chain (bit-equal to table o=0's skip-zero sum)
            float e0 = fmaf(s3f, rkd[0], 0.0f);
            e0 = fmaf(s4f,  rkd[1], e0);
            e0 = fmaf(s5f,  rkd[2], e0);
            e0 = fmaf(s6f,  rkd[3], e0);
            e0 = fmaf(s7f,  rkd[4], e0);
            e0 = fmaf(s8f,  rkd[5], e0);
            e0 = fmaf(s9f,  rkd[6], e0);
            e0 = fmaf(s10f, rkd[7], e0);
            // consume slot t = 16w+q — R4-exact tree (lB issued at t-4)
            float g = ((e0 + lB[pq][0]) + (lB[pq][1] + lB[pq][2]))
                    + ((lB[pq][3] + lB[pq][4]) + (lB[pq][5] + lB[pq][6]))
                    + (lB[pq][7] + lB[pq][8]);
            float z = (zbR[half][q] + cpipe[pq]) + g;
            z = fmaf(rk2, s2f, z);
            z = fmaf(rk1, s1f, z);
            bool sp = z > tauR[half][q];
            zarrW[q * 64] = z;                       // fire-and-forget
            // prefetch zb/tau for window w+2
            zbR[half][q]  = zbL[q * 64];
            tauR[half][q] = tauL[q * 64];
            // combo read for slot t+4 (ring; window w+1 already polled)
            cpipe[pq] = comboL[(((wbase + q + 4) & 63) << 6) + lane];
            // LUT reads for slot t+4 from PRE-shift mask (bit j = spike_{t-1-j}; j = 8o+i-2)
            lB[pq][0] = lutS[ 256 + ((m0 >> 6 ) & 255u)];
            lB[pq][1] = lutS[ 512 + ((m0 >> 14) & 255u)];
            lB[pq][2] = lutS[ 768 + ((m0 >> 22) & 255u)];
            lB[pq][3] = lutS[1024 + (__builtin_amdgcn_alignbit(m1, m0, 30) & 255u)];
            lB[pq][4] = lutS[1280 + ((m1 >> 6 ) & 255u)];
            lB[pq][5] = lutS[1536 + ((m1 >> 14) & 255u)];
            lB[pq][6] = lutS[1792 + ((m1 >> 22) & 255u)];
            lB[pq][7] = lutS[2048 + (__builtin_amdgcn_alignbit(m2, m1, 30) & 255u)];
            lB[pq][8] = lutS[2304 + ((m2 >> 6 ) & 255u)];
            // shift 96-bit history, insert this spike; shift float queue
            m2 = __builtin_amdgcn_alignbit(m2, m1, 31);
            m1 = __builtin_amdgcn_alignbit(m1, m0, 31);
            m0 = (m0 << 1) | (sp ? 1u : 0u);
            s10f = s9f; s9f = s8f; s8f = s7f; s7f = s6f; s6f = s5f;
            s5f = s4f; s4f = s3f; s3f = s2f; s2f = s1f;
            s1f = sp ? 1.0f : 0.0f;
          }
          // end of window: publish snapshots + progress
          snapL[(w & 15) * 64 + lane] = m0;
          snapA[(w & 15) * 64 + lane] = __builtin_bitreverse32(m0);
          if (lane == 0)
            __hip_atomic_store(&progLds, 16 * w + 16, __ATOMIC_RELEASE,
                               __HIP_MEMORY_SCOPE_WORKGROUP);
        }
      }
      return;
    } else if (wv == 1 || wv == 2) {
      // ================= TWIN WAVES: lags 83..162, alternating windows =================
      int par = wv - 1;
      for (int win = par; win < 128; win += 2) {
        if (win >= 4) {
          int tgt = 16 * (win - 3);
          while (__hip_atomic_load(&progLds, __ATOMIC_ACQUIRE,
                                   __HIP_MEMORY_SCOPE_WORKGROUP) < tgt)
            __builtin_amdgcn_s_sleep(1);
        }
        // pack ascending spike bits for groups win-12..win-5 into 4 words
        uint32_t a[8];
#pragma unroll
        for (int j = 0; j < 8; ++j) {
          int g = win - 12 + j;
          a[j] = (g >= 0) ? snapA[(g & 15) * 64 + lane] : 0u;
        }
        uint32_t r[4];
        r[0] = (a[0] >> 16) | (a[1] & 0xFFFF0000u);
        r[1] = (a[2] >> 16) | (a[3] & 0xFFFF0000u);
        r[2] = (a[4] >> 16) | (a[5] & 0xFFFF0000u);
        r[3] = (a[6] >> 16) | (a[7] & 0xFFFF0000u);
        float* cwp = comboL + ((16 * win) & 63) * 64 + lane;
#pragma unroll
        for (int q = 0; q < 16; ++q) {
          float acc = 0.f;
#pragma unroll
          for (int o = 10; o < 20; ++o) {
            int pos = q + 182 - 8 * o;          // low bit = spike_{s-10-8o}
            int k = pos >> 5, sh = pos & 31;
            uint32_t byt;
            if (sh <= 24) byt = (r[k] >> sh) & 255u;
            else          byt = __builtin_amdgcn_alignbit(r[k + 1], r[k], (uint32_t)sh) & 255u;
            acc += lutS[o * 256 + byt];
          }
          cwp[q * 64] = acc;
        }
        if (lane == 0)
          __hip_atomic_store(&winDone[win & 7], win + 1, __ATOMIC_RELEASE,
                             __HIP_MEMORY_SCOPE_WORKGROUP);
      }
      return;
    } else if (wv == 3) {
      // ================= STAGER: snapshots -> ballots -> sw + flags[0] =================
      for (int m = 1; m <= 64; ++m) {
        while (__hip_atomic_load(&progLds, __ATOMIC_ACQUIRE,
                                 __HIP_MEMORY_SCOPE_WORKGROUP) < 32 * m)
          __builtin_amdgcn_s_sleep(2);
        uint32_t sA = snapL[((2 * m - 2) & 15) * 64 + lane];
        uint32_t sB = snapL[((2 * m - 1) & 15) * 64 + lane];
#pragma unroll
        for (int i = 0; i < 32; ++i) {
          uint32_t sn = (i < 16) ? sA : sB;
          uint32_t bit = (sn >> (15 - (i & 15))) & 1u;
          ull bal = __ballot(bit != 0u);
          if (lane == 0) sw[32 * (m - 1) + i] = bal;
        }
        if (lane == 0)
          __hip_atomic_store(&flags[0], (uint32_t)m, __ATOMIC_RELEASE,
                             __HIP_MEMORY_SCOPE_AGENT);
      }
      return;
    }
    return;  // waves 4..7 idle
  }

  // ================= CONV BLOCKS: far lags 163..501 =================
  int c = 5 + ((int)blockIdx.x - 1) / 4;
  int qq = ((int)blockIdx.x - 1) & 3;
  int T0 = 32 * c + 8 * qq;
  int s0 = T0 - 501;
  if (tid == 0) {
    while ((int)__hip_atomic_load(&flags[0], __ATOMIC_ACQUIRE,
                                  __HIP_MEMORY_SCOPE_AGENT) < c - 4)
      __builtin_amdgcn_s_sleep(8);
  }
  __syncthreads();
  for (int i = tid; i < 384; i += 512) {
    int s = s0 + i;
    swL[i] = (s >= 0 && i < 346) ? sw[s] : 0ull;
  }
  rkL[tid] = rk[tid];
  __syncthreads();
  {
    int w8 = tid >> 6;
#pragma unroll
    for (int rep = 0; rep < 2; ++rep) {
      int W = w8 + 8 * rep;
      if (W < 12) {
        uint32_t word = 0;
        for (int i2 = 0; i2 < 32; ++i2) {
          ull v = swL[32 * W + i2];
          uint32_t bit = (uint32_t)((v >> lane) & 1ull);
          word |= bit << i2;
        }
        colb[lane * 13 + W] = word;
      }
    }
  }
  __syncthreads();
  {
    int tl = tid >> 6;           // 0..7
    int b = tid & 63;
    uint32_t cw[12];
#pragma unroll
    for (int W = 0; W < 12; ++W) cw[W] = colb[b * 13 + W];
    uint32_t A[11];
#pragma unroll
    for (int W = 0; W < 11; ++W)
      A[W] = __builtin_amdgcn_alignbit(cw[W + 1], cw[W], (uint32_t)tl);
    float acc = 0.f;
#pragma unroll 4
    for (int k = 0; k < 339; ++k) {   // lag = 501-k (501..163)
      float bv = (float)((A[k >> 5] >> (k & 31)) & 1u);
      acc = fmaf(bv, rkL[501 - k], acc);
    }
    int t = T0 + tl;
    zb[t * 64 + b] += acc;
  }
  __syncthreads();
  if (tid == 0)
    __hip_atomic_fetch_add(&flags[1 + c], 1u, __ATOMIC_RELEASE,
                           __HIP_MEMORY_SCOPE_AGENT);
}

// ---------------- post kernel ----------------
__global__ void ap_post_kernel(const float* __restrict__ zarr, const float* __restrict__ tauA,
                               float* __restrict__ out) {
#pragma clang fp contract(off)
  int idx = blockIdx.x * 256 + threadIdx.x;   // b*2048 + t
  int b = idx >> 11, t = idx & 2047;
  float z = zarr[t * 64 + b];
  float tau = tauA[t * 64 + b];
  out[idx] = (z > tau) ? 1.0f : 0.0f;
  out[131072 + idx] = 1.0f / (1.0f + __expf(-z));
}

extern "C" void kernel_launch(void* const* d_in, const int* in_sizes, int n_in,
                              void* d_out, int out_size, void* d_ws, size_t ws_size,
                              hipStream_t stream) {
  (void)in_sizes; (void)n_in; (void)out_size; (void)ws_size;
  const float* V  = (const float*)d_in[0];
  const float* D  = (const float*)d_in[1];
  const float* w1 = (const float*)d_in[2];
  const float* b1 = (const float*)d_in[3];
  const float* w2 = (const float*)d_in[4];
  const float* b2 = (const float*)d_in[5];
  const float* Wr = (const float*)d_in[6];

  char* w = (char*)d_ws;
  float*    zb    = (float*)w;                 // [2048*64]  nn + far-conv (lags>=163)
  float*    tauA  = (float*)(w + 0x080000);    // [2048*64]
  float*    zarr  = (float*)(w + 0x100000);    // [2048*64]
  ull*      swp   = (ull*)(w + 0x180000);      // [2048]
  float*    rk    = (float*)(w + 0x184000);    // [512]
  uint32_t* flags = (uint32_t*)(w + 0x184800); // [80]

  ap_pre_kernel<<<515, 256, 0, stream>>>(V, D, w1, b1, w2, b2, Wr, zb, tauA, rk, flags);
  ap_main_kernel<<<237, 512, 0, stream>>>(zb, tauA, rk, zarr, swp, flags);
  ap_post_kernel<<<512, 256, 0, stream>>>(zarr, tauA, (float*)d_out);
}